// Round 1
// baseline (1862.606 us; speedup 1.0000x reference)
//
#include <hip/hip_runtime.h>
#include <hip/hip_bf16.h>

// Problem constants (from reference)
#define BN_TOTAL   131072      // B*N = 256*512
#define T_DIM      96
#define E_NUM      8
#define H_DIM      128
#define CAP        131072      // worst-case tokens per expert
#define PTHRESH    0.05f

// d_ws layout:
//   [0, 32)                       : int cnt[8]
//   [1024, 1024+8*CAP*4)          : int toklist[8][CAP]
//   [1024+8*CAP*4, +8*CAP*4)      : float scalelist[8][CAP]

__global__ __launch_bounds__(256) void gate_kernel(
    const float* __restrict__ x, const float* __restrict__ Wg,
    const float* __restrict__ bg, const float* __restrict__ rs_p,
    float* __restrict__ mixed, float* __restrict__ util,
    int* __restrict__ cnt, int* __restrict__ toklist, float* __restrict__ scalelist)
{
    __shared__ float wg_s[E_NUM][T_DIM];
    __shared__ float bg_s[E_NUM];
    const int tid = threadIdx.x;
    for (int i = tid; i < E_NUM * T_DIM; i += 256) wg_s[i / T_DIM][i % T_DIM] = Wg[i];
    if (tid < E_NUM) bg_s[tid] = bg[tid];
    __syncthreads();

    const int token = blockIdx.x * 256 + tid;
    const float4* x4 = reinterpret_cast<const float4*>(x + (size_t)token * T_DIM);

    float logit[E_NUM];
#pragma unroll
    for (int e = 0; e < E_NUM; ++e) logit[e] = 0.0f;

#pragma unroll 4
    for (int i = 0; i < T_DIM / 4; ++i) {
        const float4 xv = x4[i];
#pragma unroll
        for (int e = 0; e < E_NUM; ++e) {
            const float4 wv = *reinterpret_cast<const float4*>(&wg_s[e][4 * i]);
            logit[e] = fmaf(xv.x, wv.x, logit[e]);
            logit[e] = fmaf(xv.y, wv.y, logit[e]);
            logit[e] = fmaf(xv.z, wv.z, logit[e]);
            logit[e] = fmaf(xv.w, wv.w, logit[e]);
        }
    }
#pragma unroll
    for (int e = 0; e < E_NUM; ++e) logit[e] = (logit[e] + bg_s[e]) / 10.0f;

    // softmax
    float mx = logit[0];
#pragma unroll
    for (int e = 1; e < E_NUM; ++e) mx = fmaxf(mx, logit[e]);
    float p[E_NUM]; float s = 0.0f;
#pragma unroll
    for (int e = 0; e < E_NUM; ++e) { p[e] = __expf(logit[e] - mx); s += p[e]; }
    const float inv_s = 1.0f / s;
#pragma unroll
    for (int e = 0; e < E_NUM; ++e) p[e] *= inv_s;

    // top-2, ties -> lower index first (strict >)
    int i0 = 0; float p0 = p[0];
#pragma unroll
    for (int e = 1; e < E_NUM; ++e) { if (p[e] > p0) { p0 = p[e]; i0 = e; } }
    int i1 = -1; float p1 = -1.0f;
#pragma unroll
    for (int e = 0; e < E_NUM; ++e) { if (e != i0 && p[e] > p1) { p1 = p[e]; i1 = e; } }

    const float denom0 = p0 + p1 + 1e-12f;
    const float w0 = p0 / denom0, w1 = p1 / denom0;
    const bool m0 = (w0 >= PTHRESH), m1 = (w1 >= PTHRESH);
    const float sumw = w0 + w1;
    const float denom1 = fmaxf(sumw, 1e-12f);
    const float wn0 = w0 / denom1, wn1 = w1 / denom1;

    const float rs = *rs_p;

    // util (B,N,E) — one-hot * mask
    float u[E_NUM];
#pragma unroll
    for (int e = 0; e < E_NUM; ++e)
        u[e] = (((e == i0) && m0) || ((e == i1) && m1)) ? 1.0f : 0.0f;
    float4* u4 = reinterpret_cast<float4*>(util + (size_t)token * E_NUM);
    u4[0] = make_float4(u[0], u[1], u[2], u[3]);
    u4[1] = make_float4(u[4], u[5], u[6], u[7]);

    // mixed init = rs * (wn0+wn1) * xf   (residual/unmasked term)
    const float coef = rs * (wn0 + wn1);
    float4* o4 = reinterpret_cast<float4*>(mixed + (size_t)token * T_DIM);
#pragma unroll 4
    for (int i = 0; i < T_DIM / 4; ++i) {
        const float4 xv = x4[i];
        o4[i] = make_float4(coef * xv.x, coef * xv.y, coef * xv.z, coef * xv.w);
    }

    // routing lists
    if (m0) {
        const int pos = atomicAdd(&cnt[i0], 1);
        toklist[i0 * CAP + pos] = token;
        scalelist[i0 * CAP + pos] = rs * wn0;
    }
    if (m1) {
        const int pos = atomicAdd(&cnt[i1], 1);
        toklist[i1 * CAP + pos] = token;
        scalelist[i1 * CAP + pos] = rs * wn1;
    }
}

#define TOKTILE 64

__global__ __launch_bounds__(256) void expert_kernel(
    const float* __restrict__ x,
    const float* __restrict__ W1, const float* __restrict__ b1,
    const float* __restrict__ W2, const float* __restrict__ b2,
    float* __restrict__ mixed,
    const int* __restrict__ cnt, const int* __restrict__ toklist,
    const float* __restrict__ scalelist)
{
    const int e = blockIdx.y;
    const int count = cnt[e];
    const int start = blockIdx.x * TOKTILE;
    if (start >= count) return;
    const int nt = min(TOKTILE, count - start);

    __shared__ float xT[T_DIM][TOKTILE];     // 24 KB, x transposed
    __shared__ float w_s[H_DIM * T_DIM];     // 48 KB, W1 then W2 (reused)
    __shared__ float hT[H_DIM][TOKTILE];     // 32 KB, h transposed
    __shared__ int   tok_s[TOKTILE];
    __shared__ float scale_s[TOKTILE];

    const int tid = threadIdx.x;
    if (tid < TOKTILE) {
        const int g = start + ((tid < nt) ? tid : 0);   // pad with slot 0 (valid addr)
        tok_s[tid] = toklist[e * CAP + g];
        scale_s[tid] = (tid < nt) ? scalelist[e * CAP + g] : 0.0f;
    }
    __syncthreads();

    // gather X -> xT  (24 float4 per token)
    for (int pidx = tid; pidx < 24 * TOKTILE; pidx += 256) {
        const int tok = pidx & 63, tq = pidx >> 6;
        const float4 v = reinterpret_cast<const float4*>(x + (size_t)tok_s[tok] * T_DIM)[tq];
        xT[4 * tq + 0][tok] = v.x; xT[4 * tq + 1][tok] = v.y;
        xT[4 * tq + 2][tok] = v.z; xT[4 * tq + 3][tok] = v.w;
    }
    // W1[e] : [96][128] row-major, linear copy
    {
        const float4* w1g = reinterpret_cast<const float4*>(W1 + (size_t)e * T_DIM * H_DIM);
        float4* wsp = reinterpret_cast<float4*>(w_s);
        for (int pidx = tid; pidx < (T_DIM * H_DIM) / 4; pidx += 256) wsp[pidx] = w1g[pidx];
    }
    __syncthreads();

    // Phase 1: H = relu(X @ W1 + b1); thread tile 4 tok x 8 col
    const int ti = (tid & 15) * 4;        // token base
    const int cj = (tid >> 4) * 8;        // hidden-col base
    float acc[4][8];
    {
        float b1v[8];
#pragma unroll
        for (int c = 0; c < 8; ++c) b1v[c] = b1[e * H_DIM + cj + c];
#pragma unroll
        for (int r = 0; r < 4; ++r)
#pragma unroll
            for (int c = 0; c < 8; ++c) acc[r][c] = b1v[c];
    }
#pragma unroll 2
    for (int t = 0; t < T_DIM; ++t) {
        const float4 xa = *reinterpret_cast<const float4*>(&xT[t][ti]);
        const float4 wa = *reinterpret_cast<const float4*>(&w_s[t * H_DIM + cj]);
        const float4 wb = *reinterpret_cast<const float4*>(&w_s[t * H_DIM + cj + 4]);
        const float xr[4] = { xa.x, xa.y, xa.z, xa.w };
        const float wc[8] = { wa.x, wa.y, wa.z, wa.w, wb.x, wb.y, wb.z, wb.w };
#pragma unroll
        for (int r = 0; r < 4; ++r)
#pragma unroll
            for (int c = 0; c < 8; ++c) acc[r][c] = fmaf(xr[r], wc[c], acc[r][c]);
    }
#pragma unroll
    for (int c = 0; c < 8; ++c) {
        const float4 hv = make_float4(fmaxf(acc[0][c], 0.0f), fmaxf(acc[1][c], 0.0f),
                                      fmaxf(acc[2][c], 0.0f), fmaxf(acc[3][c], 0.0f));
        *reinterpret_cast<float4*>(&hT[cj + c][ti]) = hv;
    }
    __syncthreads();   // phase-1 reads of w_s done; hT complete

    // W2[e] : [128][96] row-major, linear copy into same LDS
    {
        const float4* w2g = reinterpret_cast<const float4*>(W2 + (size_t)e * H_DIM * T_DIM);
        float4* wsp = reinterpret_cast<float4*>(w_s);
        for (int pidx = tid; pidx < (H_DIM * T_DIM) / 4; pidx += 256) wsp[pidx] = w2g[pidx];
    }
    __syncthreads();

    // Phase 2: Y = H @ W2; thread tile 4 tok x 6 col
    const int cy = (tid >> 4) * 6;        // out-col base (0..90)
    float acc2[4][6];
#pragma unroll
    for (int r = 0; r < 4; ++r)
#pragma unroll
        for (int c = 0; c < 6; ++c) acc2[r][c] = 0.0f;

#pragma unroll 2
    for (int h = 0; h < H_DIM; ++h) {
        const float4 ha = *reinterpret_cast<const float4*>(&hT[h][ti]);
        const float2 wv0 = *reinterpret_cast<const float2*>(&w_s[h * T_DIM + cy]);
        const float2 wv1 = *reinterpret_cast<const float2*>(&w_s[h * T_DIM + cy + 2]);
        const float2 wv2 = *reinterpret_cast<const float2*>(&w_s[h * T_DIM + cy + 4]);
        const float hr[4] = { ha.x, ha.y, ha.z, ha.w };
        const float wc[6] = { wv0.x, wv0.y, wv1.x, wv1.y, wv2.x, wv2.y };
#pragma unroll
        for (int r = 0; r < 4; ++r)
#pragma unroll
            for (int c = 0; c < 6; ++c) acc2[r][c] = fmaf(hr[r], wc[c], acc2[r][c]);
    }

    // epilogue: mixed[tok] += scale * (acc2 + b2)
    float b2v[6];
#pragma unroll
    for (int c = 0; c < 6; ++c) b2v[c] = b2[e * T_DIM + cy + c];
#pragma unroll
    for (int r = 0; r < 4; ++r) {
        const int slot = ti + r;
        if (slot < nt) {
            const float sc = scale_s[slot];
            float* orow = mixed + (size_t)tok_s[slot] * T_DIM + cy;
#pragma unroll
            for (int c = 0; c < 6; ++c)
                atomicAdd(&orow[c], sc * (acc2[r][c] + b2v[c]));
        }
    }
}

extern "C" void kernel_launch(void* const* d_in, const int* in_sizes, int n_in,
                              void* d_out, int out_size, void* d_ws, size_t ws_size,
                              hipStream_t stream)
{
    const float* x  = (const float*)d_in[0];
    const float* Wg = (const float*)d_in[1];
    const float* bg = (const float*)d_in[2];
    const float* W1 = (const float*)d_in[3];
    const float* b1 = (const float*)d_in[4];
    const float* W2 = (const float*)d_in[5];
    const float* b2 = (const float*)d_in[6];
    const float* rs = (const float*)d_in[7];

    float* mixed = (float*)d_out;
    float* util  = mixed + (size_t)BN_TOTAL * T_DIM;

    int*   cnt       = (int*)d_ws;
    int*   toklist   = (int*)((char*)d_ws + 1024);
    float* scalelist = (float*)((char*)d_ws + 1024 + (size_t)E_NUM * CAP * 4);

    hipMemsetAsync(cnt, 0, 32, stream);
    gate_kernel<<<BN_TOTAL / 256, 256, 0, stream>>>(x, Wg, bg, rs, mixed, util,
                                                    cnt, toklist, scalelist);
    expert_kernel<<<dim3(CAP / TOKTILE, E_NUM), 256, 0, stream>>>(
        x, W1, b1, W2, b2, mixed, cnt, toklist, scalelist);
}

// Round 2
// 674.356 us; speedup vs baseline: 2.7621x; 2.7621x over previous
//
#include <hip/hip_runtime.h>
#include <hip/hip_bf16.h>

#define BN_TOTAL   131072      // B*N
#define T_DIM      96
#define E_NUM      8
#define H_DIM      128
#define CAP        131072
#define PTHRESH    0.05f

// d_ws layout:
//   [0, 32)                    : int cnt[8]
//   [1024, 1024+8*CAP*4)       : int toklist[8][CAP]
//   [+8*CAP*4, +8*CAP*4)       : float scalelist[8][CAP]

__global__ __launch_bounds__(256) void gate_kernel(
    const float* __restrict__ x, const float* __restrict__ Wg,
    const float* __restrict__ bg, const float* __restrict__ rs_p,
    float* __restrict__ mixed, float* __restrict__ util,
    int* __restrict__ cnt, int* __restrict__ toklist, float* __restrict__ scalelist)
{
    __shared__ float wg_s[E_NUM][T_DIM];
    __shared__ float bg_s[E_NUM];
    __shared__ int wcnt[4][E_NUM];
    __shared__ int wbase[4][E_NUM];

    const int tid = threadIdx.x;
    for (int i = tid; i < E_NUM * T_DIM; i += 256) wg_s[i / T_DIM][i % T_DIM] = Wg[i];
    if (tid < E_NUM) bg_s[tid] = bg[tid];
    __syncthreads();

    const int token = blockIdx.x * 256 + tid;
    const float4* x4 = reinterpret_cast<const float4*>(x + (size_t)token * T_DIM);

    float logit[E_NUM];
#pragma unroll
    for (int e = 0; e < E_NUM; ++e) logit[e] = 0.0f;

#pragma unroll 4
    for (int i = 0; i < T_DIM / 4; ++i) {
        const float4 xv = x4[i];
#pragma unroll
        for (int e = 0; e < E_NUM; ++e) {
            const float4 wv = *reinterpret_cast<const float4*>(&wg_s[e][4 * i]);
            logit[e] = fmaf(xv.x, wv.x, logit[e]);
            logit[e] = fmaf(xv.y, wv.y, logit[e]);
            logit[e] = fmaf(xv.z, wv.z, logit[e]);
            logit[e] = fmaf(xv.w, wv.w, logit[e]);
        }
    }
#pragma unroll
    for (int e = 0; e < E_NUM; ++e) logit[e] = (logit[e] + bg_s[e]) / 10.0f;

    float mx = logit[0];
#pragma unroll
    for (int e = 1; e < E_NUM; ++e) mx = fmaxf(mx, logit[e]);
    float p[E_NUM]; float s = 0.0f;
#pragma unroll
    for (int e = 0; e < E_NUM; ++e) { p[e] = __expf(logit[e] - mx); s += p[e]; }
    const float inv_s = 1.0f / s;
#pragma unroll
    for (int e = 0; e < E_NUM; ++e) p[e] *= inv_s;

    int i0 = 0; float p0 = p[0];
#pragma unroll
    for (int e = 1; e < E_NUM; ++e) { if (p[e] > p0) { p0 = p[e]; i0 = e; } }
    int i1 = -1; float p1 = -1.0f;
#pragma unroll
    for (int e = 0; e < E_NUM; ++e) { if (e != i0 && p[e] > p1) { p1 = p[e]; i1 = e; } }

    const float denom0 = p0 + p1 + 1e-12f;
    const float w0 = p0 / denom0, w1 = p1 / denom0;
    const bool m0 = (w0 >= PTHRESH), m1 = (w1 >= PTHRESH);
    const float sumw = w0 + w1;
    const float denom1 = fmaxf(sumw, 1e-12f);
    const float wn0 = w0 / denom1, wn1 = w1 / denom1;
    const float rs = *rs_p;

    float u[E_NUM];
#pragma unroll
    for (int e = 0; e < E_NUM; ++e)
        u[e] = (((e == i0) && m0) || ((e == i1) && m1)) ? 1.0f : 0.0f;
    float4* u4 = reinterpret_cast<float4*>(util + (size_t)token * E_NUM);
    u4[0] = make_float4(u[0], u[1], u[2], u[3]);
    u4[1] = make_float4(u[4], u[5], u[6], u[7]);

    const float coef = rs * (wn0 + wn1);
    float4* o4 = reinterpret_cast<float4*>(mixed + (size_t)token * T_DIM);
#pragma unroll 4
    for (int i = 0; i < T_DIM / 4; ++i) {
        const float4 xv = x4[i];
        o4[i] = make_float4(coef * xv.x, coef * xv.y, coef * xv.z, coef * xv.w);
    }

    // ---- two-level aggregated routing-list append ----
    const int lane = tid & 63;
    const int wv_id = tid >> 6;
    const unsigned long long lt = (1ULL << lane) - 1ULL;

    int wcnt_mine = 0, offA = 0, offB = 0;
#pragma unroll
    for (int e = 0; e < E_NUM; ++e) {
        const unsigned long long A = __ballot(m0 && (i0 == e));
        const unsigned long long B = __ballot(m1 && (i1 == e));
        const int na = __popcll(A), nb = __popcll(B);
        if (lane == e) wcnt_mine = na + nb;
        if (m0 && (i0 == e)) offA = __popcll(A & lt);
        if (m1 && (i1 == e)) offB = na + __popcll(B & lt);
    }
    if (lane < E_NUM) wcnt[wv_id][lane] = wcnt_mine;
    __syncthreads();
    if (tid < E_NUM) {
        const int c0 = wcnt[0][tid], c1 = wcnt[1][tid], c2 = wcnt[2][tid], c3 = wcnt[3][tid];
        const int g = atomicAdd(&cnt[tid], c0 + c1 + c2 + c3);
        wbase[0][tid] = g;
        wbase[1][tid] = g + c0;
        wbase[2][tid] = g + c0 + c1;
        wbase[3][tid] = g + c0 + c1 + c2;
    }
    __syncthreads();
    if (m0) {
        const int pos = wbase[wv_id][i0] + offA;
        toklist[i0 * CAP + pos] = token;
        scalelist[i0 * CAP + pos] = rs * wn0;
    }
    if (m1) {
        const int pos = wbase[wv_id][i1] + offB;
        toklist[i1 * CAP + pos] = token;
        scalelist[i1 * CAP + pos] = rs * wn1;
    }
}

#define TOKTILE 128
// LDS overlay: phase1 {xT[96][128] | w_lo[96][64] | w_hi[96][64]} = 24576 floats
//              phase2 {hT[128][128] (0..16384) | W2[128*96] (16384..28672)}
#define BUF_FLOATS 28672

__global__ __launch_bounds__(256) void expert_kernel(
    const float* __restrict__ x,
    const float* __restrict__ W1, const float* __restrict__ b1,
    const float* __restrict__ W2, const float* __restrict__ b2,
    float* __restrict__ mixed,
    const int* __restrict__ cnt, const int* __restrict__ toklist,
    const float* __restrict__ scalelist)
{
    const int e = blockIdx.y;
    const int count = cnt[e];
    const int start = blockIdx.x * TOKTILE;
    if (start >= count) return;
    const int nt = min(TOKTILE, count - start);

    __shared__ float buf[BUF_FLOATS];
    __shared__ int   tok_s[TOKTILE];
    __shared__ float scale_s[TOKTILE];

    float* xT   = buf;                    // [96][128]
    float* w_lo = buf + 12288;            // [96][64]
    float* w_hi = buf + 12288 + 6144;     // [96][64]
    float* hT   = buf;                    // [128][128]  (phase2)
    float* w2s  = buf + 16384;            // [128][96]   (phase2)

    const int tid = threadIdx.x;
    if (tid < TOKTILE) {
        const int g = start + ((tid < nt) ? tid : 0);
        tok_s[tid] = toklist[e * CAP + g];
        scale_s[tid] = (tid < nt) ? scalelist[e * CAP + g] : 0.0f;
    }
    __syncthreads();

    // gather X -> xT[t][tok]
    for (int pidx = tid; pidx < 24 * TOKTILE; pidx += 256) {
        const int tok = pidx & (TOKTILE - 1), tq = pidx >> 7;
        const float4 v = reinterpret_cast<const float4*>(x + (size_t)tok_s[tok] * T_DIM)[tq];
        xT[(4 * tq + 0) * TOKTILE + tok] = v.x;
        xT[(4 * tq + 1) * TOKTILE + tok] = v.y;
        xT[(4 * tq + 2) * TOKTILE + tok] = v.z;
        xT[(4 * tq + 3) * TOKTILE + tok] = v.w;
    }
    // stage W1 -> lo/hi split: w_lo[t][4c..]=W1[t][8c..8c+3], w_hi=W1[t][8c+4..]
    {
        const float4* w1g = reinterpret_cast<const float4*>(W1 + (size_t)e * T_DIM * H_DIM);
        for (int idx = tid; idx < 96 * 16; idx += 256) {
            const int t = idx >> 4, c = idx & 15;
            const float4 a = w1g[t * 32 + 2 * c];
            const float4 b = w1g[t * 32 + 2 * c + 1];
            *reinterpret_cast<float4*>(&w_lo[t * 64 + 4 * c]) = a;
            *reinterpret_cast<float4*>(&w_hi[t * 64 + 4 * c]) = b;
        }
    }
    __syncthreads();

    // Phase 1: h = relu(X @ W1 + b1); thread tile 8 tok x 8 hid, kept in regs
    const int tg = tid >> 4;              // 0..15, token group
    const int cg = tid & 15;              // 0..15, hid group
    const int ti = tg * 8;
    const int cj = cg * 8;

    float acc[8][8];
    {
        float b1v[8];
        const float4* b1g = reinterpret_cast<const float4*>(b1 + (size_t)e * H_DIM + cj);
        const float4 bva = b1g[0], bvb = b1g[1];
        b1v[0] = bva.x; b1v[1] = bva.y; b1v[2] = bva.z; b1v[3] = bva.w;
        b1v[4] = bvb.x; b1v[5] = bvb.y; b1v[6] = bvb.z; b1v[7] = bvb.w;
#pragma unroll
        for (int r = 0; r < 8; ++r)
#pragma unroll
            for (int c = 0; c < 8; ++c) acc[r][c] = b1v[c];
    }
#pragma unroll 4
    for (int t = 0; t < T_DIM; ++t) {
        const float4 xa = *reinterpret_cast<const float4*>(&xT[t * TOKTILE + ti]);
        const float4 xb = *reinterpret_cast<const float4*>(&xT[t * TOKTILE + ti + 4]);
        const float4 wa = *reinterpret_cast<const float4*>(&w_lo[t * 64 + 4 * cg]);
        const float4 wb = *reinterpret_cast<const float4*>(&w_hi[t * 64 + 4 * cg]);
        const float xr[8] = { xa.x, xa.y, xa.z, xa.w, xb.x, xb.y, xb.z, xb.w };
        const float wc[8] = { wa.x, wa.y, wa.z, wa.w, wb.x, wb.y, wb.z, wb.w };
#pragma unroll
        for (int r = 0; r < 8; ++r)
#pragma unroll
            for (int c = 0; c < 8; ++c) acc[r][c] = fmaf(xr[r], wc[c], acc[r][c]);
    }
#pragma unroll
    for (int r = 0; r < 8; ++r)
#pragma unroll
        for (int c = 0; c < 8; ++c) acc[r][c] = fmaxf(acc[r][c], 0.0f);

    __syncthreads();   // all phase-1 LDS reads complete; buf reusable

    // write h (regs) -> hT[h][tok]; stage W2 -> w2s
#pragma unroll
    for (int c = 0; c < 8; ++c) {
        *reinterpret_cast<float4*>(&hT[(cj + c) * TOKTILE + ti]) =
            make_float4(acc[0][c], acc[1][c], acc[2][c], acc[3][c]);
        *reinterpret_cast<float4*>(&hT[(cj + c) * TOKTILE + ti + 4]) =
            make_float4(acc[4][c], acc[5][c], acc[6][c], acc[7][c]);
    }
    {
        const float4* w2g = reinterpret_cast<const float4*>(W2 + (size_t)e * H_DIM * T_DIM);
        float4* d = reinterpret_cast<float4*>(w2s);
        for (int idx = tid; idx < (H_DIM * T_DIM) / 4; idx += 256) d[idx] = w2g[idx];
    }
    __syncthreads();

    // Phase 2: y = h @ W2; thread tile 8 tok x 6 col
    const int cy = cg * 6;
    float acc2[8][6];
#pragma unroll
    for (int r = 0; r < 8; ++r)
#pragma unroll
        for (int c = 0; c < 6; ++c) acc2[r][c] = 0.0f;

#pragma unroll 4
    for (int h = 0; h < H_DIM; ++h) {
        const float4 ha = *reinterpret_cast<const float4*>(&hT[h * TOKTILE + ti]);
        const float4 hb = *reinterpret_cast<const float4*>(&hT[h * TOKTILE + ti + 4]);
        const float2 wv0 = *reinterpret_cast<const float2*>(&w2s[h * T_DIM + cy]);
        const float2 wv1 = *reinterpret_cast<const float2*>(&w2s[h * T_DIM + cy + 2]);
        const float2 wv2 = *reinterpret_cast<const float2*>(&w2s[h * T_DIM + cy + 4]);
        const float hr[8] = { ha.x, ha.y, ha.z, ha.w, hb.x, hb.y, hb.z, hb.w };
        const float wc[6] = { wv0.x, wv0.y, wv1.x, wv1.y, wv2.x, wv2.y };
#pragma unroll
        for (int r = 0; r < 8; ++r)
#pragma unroll
            for (int c = 0; c < 6; ++c) acc2[r][c] = fmaf(hr[r], wc[c], acc2[r][c]);
    }

    float b2v[6];
#pragma unroll
    for (int c = 0; c < 6; ++c) b2v[c] = b2[e * T_DIM + cy + c];
#pragma unroll
    for (int r = 0; r < 8; ++r) {
        const int slot = ti + r;
        if (slot < nt) {
            const float sc = scale_s[slot];
            float* orow = mixed + (size_t)tok_s[slot] * T_DIM + cy;
#pragma unroll
            for (int c = 0; c < 6; ++c)
                atomicAdd(&orow[c], sc * (acc2[r][c] + b2v[c]));
        }
    }
}

extern "C" void kernel_launch(void* const* d_in, const int* in_sizes, int n_in,
                              void* d_out, int out_size, void* d_ws, size_t ws_size,
                              hipStream_t stream)
{
    const float* x  = (const float*)d_in[0];
    const float* Wg = (const float*)d_in[1];
    const float* bg = (const float*)d_in[2];
    const float* W1 = (const float*)d_in[3];
    const float* b1 = (const float*)d_in[4];
    const float* W2 = (const float*)d_in[5];
    const float* b2 = (const float*)d_in[6];
    const float* rs = (const float*)d_in[7];

    float* mixed = (float*)d_out;
    float* util  = mixed + (size_t)BN_TOTAL * T_DIM;

    int*   cnt       = (int*)d_ws;
    int*   toklist   = (int*)((char*)d_ws + 1024);
    float* scalelist = (float*)((char*)d_ws + 1024 + (size_t)E_NUM * CAP * 4);

    hipMemsetAsync(cnt, 0, 32, stream);
    gate_kernel<<<BN_TOTAL / 256, 256, 0, stream>>>(x, Wg, bg, rs, mixed, util,
                                                    cnt, toklist, scalelist);
    expert_kernel<<<dim3(CAP / TOKTILE, E_NUM), 256, 0, stream>>>(
        x, W1, b1, W2, b2, mixed, cnt, toklist, scalelist);
}

// Round 4
// 248.380 us; speedup vs baseline: 7.4990x; 2.7150x over previous
//
#include <hip/hip_runtime.h>
#include <hip/hip_bf16.h>

#define BN_TOTAL   131072      // B*N
#define T_DIM      96
#define E_NUM      8
#define H_DIM      128
#define CAP        131072
#define PTHRESH    0.05f

// ---- workspace layout (bytes) ----
#define OFF_TOK    1024
#define OFF_SCALE  (OFF_TOK   + E_NUM * CAP * 4)
#define OFF_MASK   (OFF_SCALE + E_NUM * CAP * 4)
#define OFF_COEF   (OFF_MASK  + BN_TOTAL * 4)
#define OFF_YBUF   (OFF_COEF  + BN_TOTAL * 4)
#define WS_NEED    ((size_t)OFF_YBUF + (size_t)2 * BN_TOTAL * T_DIM * 4)

// toklist entries are PACKED: (token<<1) | k, where k=0 -> token's first
// (m0) expert entry, k=1 -> second (m1). ybuf row id == packed value, so
// ybuf needs exactly 2*BN rows regardless of expert balance (round-3 fix).

template<bool GATHER>
__global__ __launch_bounds__(256) void gate_kernel(
    const float* __restrict__ x, const float* __restrict__ Wg,
    const float* __restrict__ bg, const float* __restrict__ rs_p,
    float* __restrict__ mixed, float* __restrict__ util,
    int* __restrict__ cnt, int* __restrict__ toklist, float* __restrict__ scalelist,
    int* __restrict__ maskbuf, float* __restrict__ coefbuf)
{
    __shared__ float wg_s[E_NUM][T_DIM];
    __shared__ float bg_s[E_NUM];
    __shared__ int wcnt[4][E_NUM];
    __shared__ int wbase[4][E_NUM];

    const int tid = threadIdx.x;
    for (int i = tid; i < E_NUM * T_DIM; i += 256) wg_s[i / T_DIM][i % T_DIM] = Wg[i];
    if (tid < E_NUM) bg_s[tid] = bg[tid];
    __syncthreads();

    const int token = blockIdx.x * 256 + tid;
    const float4* x4 = reinterpret_cast<const float4*>(x + (size_t)token * T_DIM);

    float logit[E_NUM];
#pragma unroll
    for (int e = 0; e < E_NUM; ++e) logit[e] = 0.0f;

#pragma unroll 4
    for (int i = 0; i < T_DIM / 4; ++i) {
        const float4 xv = x4[i];
#pragma unroll
        for (int e = 0; e < E_NUM; ++e) {
            const float4 wv = *reinterpret_cast<const float4*>(&wg_s[e][4 * i]);
            logit[e] = fmaf(xv.x, wv.x, logit[e]);
            logit[e] = fmaf(xv.y, wv.y, logit[e]);
            logit[e] = fmaf(xv.z, wv.z, logit[e]);
            logit[e] = fmaf(xv.w, wv.w, logit[e]);
        }
    }
#pragma unroll
    for (int e = 0; e < E_NUM; ++e) logit[e] = (logit[e] + bg_s[e]) / 10.0f;

    float mx = logit[0];
#pragma unroll
    for (int e = 1; e < E_NUM; ++e) mx = fmaxf(mx, logit[e]);
    float p[E_NUM]; float s = 0.0f;
#pragma unroll
    for (int e = 0; e < E_NUM; ++e) { p[e] = __expf(logit[e] - mx); s += p[e]; }
    const float inv_s = 1.0f / s;
#pragma unroll
    for (int e = 0; e < E_NUM; ++e) p[e] *= inv_s;

    int i0 = 0; float p0 = p[0];
#pragma unroll
    for (int e = 1; e < E_NUM; ++e) { if (p[e] > p0) { p0 = p[e]; i0 = e; } }
    int i1 = -1; float p1 = -1.0f;
#pragma unroll
    for (int e = 0; e < E_NUM; ++e) { if (e != i0 && p[e] > p1) { p1 = p[e]; i1 = e; } }

    const float denom0 = p0 + p1 + 1e-12f;
    const float w0 = p0 / denom0, w1 = p1 / denom0;
    const bool m0 = (w0 >= PTHRESH), m1 = (w1 >= PTHRESH);
    const float sumw = w0 + w1;
    const float denom1 = fmaxf(sumw, 1e-12f);
    const float wn0 = w0 / denom1, wn1 = w1 / denom1;
    const float rs = *rs_p;

    float u[E_NUM];
#pragma unroll
    for (int e = 0; e < E_NUM; ++e)
        u[e] = (((e == i0) && m0) || ((e == i1) && m1)) ? 1.0f : 0.0f;
    float4* u4 = reinterpret_cast<float4*>(util + (size_t)token * E_NUM);
    u4[0] = make_float4(u[0], u[1], u[2], u[3]);
    u4[1] = make_float4(u[4], u[5], u[6], u[7]);

    const float coef = rs * (wn0 + wn1);
    if (GATHER) {
        coefbuf[token] = coef;
        maskbuf[token] = (m0 ? 1 : 0) | (m1 ? 2 : 0);
    } else {
        float4* o4 = reinterpret_cast<float4*>(mixed + (size_t)token * T_DIM);
#pragma unroll 4
        for (int i = 0; i < T_DIM / 4; ++i) {
            const float4 xv = x4[i];
            o4[i] = make_float4(coef * xv.x, coef * xv.y, coef * xv.z, coef * xv.w);
        }
    }

    // ---- two-level aggregated routing-list append ----
    const int lane = tid & 63;
    const int wv_id = tid >> 6;
    const unsigned long long lt = (1ULL << lane) - 1ULL;

    int wcnt_mine = 0, offA = 0, offB = 0;
#pragma unroll
    for (int e = 0; e < E_NUM; ++e) {
        const unsigned long long A = __ballot(m0 && (i0 == e));
        const unsigned long long B = __ballot(m1 && (i1 == e));
        const int na = __popcll(A), nb = __popcll(B);
        if (lane == e) wcnt_mine = na + nb;
        if (m0 && (i0 == e)) offA = __popcll(A & lt);
        if (m1 && (i1 == e)) offB = na + __popcll(B & lt);
    }
    if (lane < E_NUM) wcnt[wv_id][lane] = wcnt_mine;
    __syncthreads();
    if (tid < E_NUM) {
        const int c0 = wcnt[0][tid], c1 = wcnt[1][tid], c2 = wcnt[2][tid], c3 = wcnt[3][tid];
        const int g = atomicAdd(&cnt[tid], c0 + c1 + c2 + c3);
        wbase[0][tid] = g;
        wbase[1][tid] = g + c0;
        wbase[2][tid] = g + c0 + c1;
        wbase[3][tid] = g + c0 + c1 + c2;
    }
    __syncthreads();

    if (m0) {
        const int pos = wbase[wv_id][i0] + offA;
        toklist[i0 * CAP + pos] = (token << 1);        // k=0
        scalelist[i0 * CAP + pos] = rs * wn0;
    }
    if (m1) {
        const int pos = wbase[wv_id][i1] + offB;
        toklist[i1 * CAP + pos] = (token << 1) | 1;    // k=1
        scalelist[i1 * CAP + pos] = rs * wn1;
    }
}

#define TOKTILE 64
// LDS union (floats):
//  phase1: xT[96][64] @0 | w_lo[96][64] @6144 | w_hi[96][64] @12288  = 18432
//  phase2: hT[128][64] @0 (XOR-swizzled)     | w2s[128][96] @8192   = 20480
#define BUF_FLOATS 20480

__device__ __forceinline__ int hidx(int row, int col) {
    return row * 64 + (col ^ (((row >> 3) & 15) << 2));
}

template<bool GATHER>
__global__ __launch_bounds__(256, 2) void expert_kernel(
    const float* __restrict__ x,
    const float* __restrict__ W1, const float* __restrict__ b1,
    const float* __restrict__ W2, const float* __restrict__ b2,
    float* __restrict__ mixed, float* __restrict__ ybuf,
    const int* __restrict__ cnt, const int* __restrict__ toklist,
    const float* __restrict__ scalelist)
{
    const int e = blockIdx.y;
    const int count = cnt[e];
    const int start = blockIdx.x * TOKTILE;
    if (start >= count) return;
    const int nt = min(TOKTILE, count - start);

    __shared__ __align__(16) float buf[BUF_FLOATS];
    float* xT   = buf;            // [96][64]
    float* w_lo = buf + 6144;     // [96][64]
    float* w_hi = buf + 12288;    // [96][64]
    float* hT   = buf;            // [128][64] swizzled (phase2)
    float* w2s  = buf + 8192;     // [128][96]          (phase2)

    const int tid = threadIdx.x;
    const int* tl = toklist + (size_t)e * CAP + start;   // packed (token<<1)|k

    // gather X -> xT[t][tok]
    for (int pidx = tid; pidx < 24 * TOKTILE; pidx += 256) {
        const int tok = pidx & (TOKTILE - 1), tq = pidx >> 6;
        const int g = (tok < nt) ? tok : 0;
        const int row = tl[g] >> 1;
        const float4 v = reinterpret_cast<const float4*>(x + (size_t)row * T_DIM)[tq];
        xT[(4 * tq + 0) * TOKTILE + tok] = v.x;
        xT[(4 * tq + 1) * TOKTILE + tok] = v.y;
        xT[(4 * tq + 2) * TOKTILE + tok] = v.z;
        xT[(4 * tq + 3) * TOKTILE + tok] = v.w;
    }
    // stage W1 lo/hi split
    {
        const float4* w1g = reinterpret_cast<const float4*>(W1 + (size_t)e * T_DIM * H_DIM);
        for (int idx = tid; idx < 96 * 16; idx += 256) {
            const int t = idx >> 4, c = idx & 15;
            const float4 a = w1g[t * 32 + 2 * c];
            const float4 b = w1g[t * 32 + 2 * c + 1];
            *reinterpret_cast<float4*>(&w_lo[t * 64 + 4 * c]) = a;
            *reinterpret_cast<float4*>(&w_hi[t * 64 + 4 * c]) = b;
        }
    }
    __syncthreads();

    // Phase 1: h = relu(X@W1 + b1); tile 4tok x 8hid
    const int tg = tid >> 4;          // 0..15
    const int cg = tid & 15;          // 0..15
    const int ti = tg * 4;
    const int cj = cg * 8;

    float acc[4][8];
    {
        const float4* b1g = reinterpret_cast<const float4*>(b1 + (size_t)e * H_DIM + cj);
        const float4 bva = b1g[0], bvb = b1g[1];
        const float b1v[8] = { bva.x, bva.y, bva.z, bva.w, bvb.x, bvb.y, bvb.z, bvb.w };
#pragma unroll
        for (int r = 0; r < 4; ++r)
#pragma unroll
            for (int c = 0; c < 8; ++c) acc[r][c] = b1v[c];
    }
#pragma unroll 4
    for (int t = 0; t < T_DIM; ++t) {
        const float4 xa = *reinterpret_cast<const float4*>(&xT[t * TOKTILE + ti]);
        const float4 wa = *reinterpret_cast<const float4*>(&w_lo[t * 64 + 4 * cg]);
        const float4 wb = *reinterpret_cast<const float4*>(&w_hi[t * 64 + 4 * cg]);
        const float xr[4] = { xa.x, xa.y, xa.z, xa.w };
        const float wc[8] = { wa.x, wa.y, wa.z, wa.w, wb.x, wb.y, wb.z, wb.w };
#pragma unroll
        for (int r = 0; r < 4; ++r)
#pragma unroll
            for (int c = 0; c < 8; ++c) acc[r][c] = fmaf(xr[r], wc[c], acc[r][c]);
    }
    __syncthreads();   // phase-1 LDS reads done; buf reusable

    // h -> hT (swizzled), stage W2
#pragma unroll
    for (int c = 0; c < 8; ++c) {
        const float4 hv = make_float4(fmaxf(acc[0][c], 0.0f), fmaxf(acc[1][c], 0.0f),
                                      fmaxf(acc[2][c], 0.0f), fmaxf(acc[3][c], 0.0f));
        *reinterpret_cast<float4*>(&hT[hidx(cj + c, ti)]) = hv;
    }
    {
        const float4* w2g = reinterpret_cast<const float4*>(W2 + (size_t)e * H_DIM * T_DIM);
        float4* d = reinterpret_cast<float4*>(w2s);
        for (int idx = tid; idx < (H_DIM * T_DIM) / 4; idx += 256) d[idx] = w2g[idx];
    }
    __syncthreads();

    // Phase 2: y = h@W2; tile 4tok x 6out
    const int cy = cg * 6;
    float acc2[4][6];
#pragma unroll
    for (int r = 0; r < 4; ++r)
#pragma unroll
        for (int c = 0; c < 6; ++c) acc2[r][c] = 0.0f;

#pragma unroll 4
    for (int h = 0; h < H_DIM; ++h) {
        const float4 ha = *reinterpret_cast<const float4*>(&hT[hidx(h, ti)]);
        const float2 wv0 = *reinterpret_cast<const float2*>(&w2s[h * T_DIM + cy]);
        const float2 wv1 = *reinterpret_cast<const float2*>(&w2s[h * T_DIM + cy + 2]);
        const float2 wv2 = *reinterpret_cast<const float2*>(&w2s[h * T_DIM + cy + 4]);
        const float hr[4] = { ha.x, ha.y, ha.z, ha.w };
        const float wc[6] = { wv0.x, wv0.y, wv1.x, wv1.y, wv2.x, wv2.y };
#pragma unroll
        for (int r = 0; r < 4; ++r)
#pragma unroll
            for (int c = 0; c < 6; ++c) acc2[r][c] = fmaf(hr[r], wc[c], acc2[r][c]);
    }

    float b2v[6];
#pragma unroll
    for (int c = 0; c < 6; ++c) b2v[c] = b2[e * T_DIM + cy + c];

    const float* sl = scalelist + (size_t)e * CAP + start;
#pragma unroll
    for (int r = 0; r < 4; ++r) {
        const int slot = ti + r;
        if (slot < nt) {
            const float sc = sl[slot];
            const int packed = tl[slot];
            if (GATHER) {
                // ybuf row = packed id (2*token+k), guaranteed < 2*BN
                float* orow = ybuf + (size_t)packed * T_DIM + cy;
#pragma unroll
                for (int c = 0; c < 6; c += 2)
                    *reinterpret_cast<float2*>(&orow[c]) =
                        make_float2(sc * (acc2[r][c] + b2v[c]), sc * (acc2[r][c + 1] + b2v[c + 1]));
            } else {
                float* orow = mixed + (size_t)(packed >> 1) * T_DIM + cy;
#pragma unroll
                for (int c = 0; c < 6; ++c)
                    atomicAdd(&orow[c], sc * (acc2[r][c] + b2v[c]));
            }
        }
    }
}

// mixed[tok] = coef*x[tok] + (mask&1 ? ybuf[2t] : 0) + (mask&2 ? ybuf[2t+1] : 0)
__global__ __launch_bounds__(256) void finalize_kernel(
    const float* __restrict__ x, const float* __restrict__ ybuf,
    const int* __restrict__ maskbuf, const float* __restrict__ coefbuf,
    float* __restrict__ mixed)
{
    const int tid = threadIdx.x;
    const int token = blockIdx.x * 32 + (tid >> 3);
    const int seg = (tid & 7) * 12;

    const float coef = coefbuf[token];
    const int mask = maskbuf[token];

    const float4* xs = reinterpret_cast<const float4*>(x + (size_t)token * T_DIM + seg);
    float4* od = reinterpret_cast<float4*>(mixed + (size_t)token * T_DIM + seg);

    float4 r[3];
#pragma unroll
    for (int q = 0; q < 3; ++q) {
        const float4 xv = xs[q];
        r[q] = make_float4(coef * xv.x, coef * xv.y, coef * xv.z, coef * xv.w);
    }
    if (mask & 1) {
        const float4* ys = reinterpret_cast<const float4*>(ybuf + (size_t)(2 * token) * T_DIM + seg);
#pragma unroll
        for (int q = 0; q < 3; ++q) {
            const float4 yv = ys[q];
            r[q].x += yv.x; r[q].y += yv.y; r[q].z += yv.z; r[q].w += yv.w;
        }
    }
    if (mask & 2) {
        const float4* ys = reinterpret_cast<const float4*>(ybuf + (size_t)(2 * token + 1) * T_DIM + seg);
#pragma unroll
        for (int q = 0; q < 3; ++q) {
            const float4 yv = ys[q];
            r[q].x += yv.x; r[q].y += yv.y; r[q].z += yv.z; r[q].w += yv.w;
        }
    }
#pragma unroll
    for (int q = 0; q < 3; ++q) od[q] = r[q];
}

extern "C" void kernel_launch(void* const* d_in, const int* in_sizes, int n_in,
                              void* d_out, int out_size, void* d_ws, size_t ws_size,
                              hipStream_t stream)
{
    const float* x  = (const float*)d_in[0];
    const float* Wg = (const float*)d_in[1];
    const float* bg = (const float*)d_in[2];
    const float* W1 = (const float*)d_in[3];
    const float* b1 = (const float*)d_in[4];
    const float* W2 = (const float*)d_in[5];
    const float* b2 = (const float*)d_in[6];
    const float* rs = (const float*)d_in[7];

    float* mixed = (float*)d_out;
    float* util  = mixed + (size_t)BN_TOTAL * T_DIM;

    char* ws = (char*)d_ws;
    int*   cnt       = (int*)ws;
    int*   toklist   = (int*)(ws + OFF_TOK);
    float* scalelist = (float*)(ws + OFF_SCALE);
    int*   maskbuf   = (int*)(ws + OFF_MASK);
    float* coefbuf   = (float*)(ws + OFF_COEF);
    float* ybuf      = (float*)(ws + OFF_YBUF);

    const bool gather = (ws_size >= WS_NEED);

    hipMemsetAsync(cnt, 0, 32, stream);
    if (gather) {
        gate_kernel<true><<<BN_TOTAL / 256, 256, 0, stream>>>(
            x, Wg, bg, rs, mixed, util, cnt, toklist, scalelist, maskbuf, coefbuf);
        expert_kernel<true><<<dim3(CAP / TOKTILE, E_NUM), 256, 0, stream>>>(
            x, W1, b1, W2, b2, mixed, ybuf, cnt, toklist, scalelist);
        finalize_kernel<<<BN_TOTAL / 32, 256, 0, stream>>>(
            x, ybuf, maskbuf, coefbuf, mixed);
    } else {
        gate_kernel<false><<<BN_TOTAL / 256, 256, 0, stream>>>(
            x, Wg, bg, rs, mixed, util, cnt, toklist, scalelist, maskbuf, coefbuf);
        expert_kernel<false><<<dim3(CAP / TOKTILE, E_NUM), 256, 0, stream>>>(
            x, W1, b1, W2, b2, mixed, ybuf, cnt, toklist, scalelist);
    }
}

// Round 5
// 125.665 us; speedup vs baseline: 14.8220x; 1.9765x over previous
//
#include <hip/hip_runtime.h>
#include <hip/hip_bf16.h>

#define BN_TOTAL   131072      // B*N
#define T_DIM      96
#define E_NUM      8
#define H_DIM      128
#define CAP        131072
#define PTHRESH    0.05f
#define NBLK       64          // expert-kernel blocks per expert

typedef _Float16 f16x8 __attribute__((ext_vector_type(8)));
typedef _Float16 f16x4 __attribute__((ext_vector_type(4)));
typedef float    f32x4 __attribute__((ext_vector_type(4)));

// ---- workspace layout (bytes) ----
#define OFF_TOK    1024
#define OFF_SCALE  (OFF_TOK   + E_NUM * CAP * 4)
#define OFF_MASK   (OFF_SCALE + E_NUM * CAP * 4)
#define OFF_COEF   (OFF_MASK  + BN_TOTAL * 4)
#define OFF_YBUF   (OFF_COEF  + BN_TOTAL * 4)
#define WS_NEED    ((size_t)OFF_YBUF + (size_t)2 * BN_TOTAL * T_DIM * 4)

// toklist entries PACKED: (token<<1)|k ; ybuf row id == packed value (< 2*BN).

template<bool GATHER>
__global__ __launch_bounds__(256) void gate_kernel(
    const float* __restrict__ x, const float* __restrict__ Wg,
    const float* __restrict__ bg, const float* __restrict__ rs_p,
    float* __restrict__ mixed, float* __restrict__ util,
    int* __restrict__ cnt, int* __restrict__ toklist, float* __restrict__ scalelist,
    int* __restrict__ maskbuf, float* __restrict__ coefbuf)
{
    __shared__ float wg_s[E_NUM][T_DIM];
    __shared__ float bg_s[E_NUM];
    __shared__ int wcnt[4][E_NUM];
    __shared__ int wbase[4][E_NUM];

    const int tid = threadIdx.x;
    for (int i = tid; i < E_NUM * T_DIM; i += 256) wg_s[i / T_DIM][i % T_DIM] = Wg[i];
    if (tid < E_NUM) bg_s[tid] = bg[tid];
    __syncthreads();

    const int token = blockIdx.x * 256 + tid;
    const float4* x4 = reinterpret_cast<const float4*>(x + (size_t)token * T_DIM);

    float logit[E_NUM];
#pragma unroll
    for (int e = 0; e < E_NUM; ++e) logit[e] = 0.0f;

#pragma unroll 4
    for (int i = 0; i < T_DIM / 4; ++i) {
        const float4 xv = x4[i];
#pragma unroll
        for (int e = 0; e < E_NUM; ++e) {
            const float4 wv = *reinterpret_cast<const float4*>(&wg_s[e][4 * i]);
            logit[e] = fmaf(xv.x, wv.x, logit[e]);
            logit[e] = fmaf(xv.y, wv.y, logit[e]);
            logit[e] = fmaf(xv.z, wv.z, logit[e]);
            logit[e] = fmaf(xv.w, wv.w, logit[e]);
        }
    }
#pragma unroll
    for (int e = 0; e < E_NUM; ++e) logit[e] = (logit[e] + bg_s[e]) / 10.0f;

    float mx = logit[0];
#pragma unroll
    for (int e = 1; e < E_NUM; ++e) mx = fmaxf(mx, logit[e]);
    float p[E_NUM]; float s = 0.0f;
#pragma unroll
    for (int e = 0; e < E_NUM; ++e) { p[e] = __expf(logit[e] - mx); s += p[e]; }
    const float inv_s = 1.0f / s;
#pragma unroll
    for (int e = 0; e < E_NUM; ++e) p[e] *= inv_s;

    int i0 = 0; float p0 = p[0];
#pragma unroll
    for (int e = 1; e < E_NUM; ++e) { if (p[e] > p0) { p0 = p[e]; i0 = e; } }
    int i1 = -1; float p1 = -1.0f;
#pragma unroll
    for (int e = 0; e < E_NUM; ++e) { if (e != i0 && p[e] > p1) { p1 = p[e]; i1 = e; } }

    const float denom0 = p0 + p1 + 1e-12f;
    const float w0 = p0 / denom0, w1 = p1 / denom0;
    const bool m0 = (w0 >= PTHRESH), m1 = (w1 >= PTHRESH);
    const float sumw = w0 + w1;
    const float denom1 = fmaxf(sumw, 1e-12f);
    const float wn0 = w0 / denom1, wn1 = w1 / denom1;
    const float rs = *rs_p;

    float u[E_NUM];
#pragma unroll
    for (int e = 0; e < E_NUM; ++e)
        u[e] = (((e == i0) && m0) || ((e == i1) && m1)) ? 1.0f : 0.0f;
    float4* u4 = reinterpret_cast<float4*>(util + (size_t)token * E_NUM);
    u4[0] = make_float4(u[0], u[1], u[2], u[3]);
    u4[1] = make_float4(u[4], u[5], u[6], u[7]);

    const float coef = rs * (wn0 + wn1);
    if (GATHER) {
        coefbuf[token] = coef;
        maskbuf[token] = (m0 ? 1 : 0) | (m1 ? 2 : 0);
    } else {
        float4* o4 = reinterpret_cast<float4*>(mixed + (size_t)token * T_DIM);
#pragma unroll 4
        for (int i = 0; i < T_DIM / 4; ++i) {
            const float4 xv = x4[i];
            o4[i] = make_float4(coef * xv.x, coef * xv.y, coef * xv.z, coef * xv.w);
        }
    }

    // ---- two-level aggregated routing-list append ----
    const int lane = tid & 63;
    const int wv_id = tid >> 6;
    const unsigned long long lt = (1ULL << lane) - 1ULL;

    int wcnt_mine = 0, offA = 0, offB = 0;
#pragma unroll
    for (int e = 0; e < E_NUM; ++e) {
        const unsigned long long A = __ballot(m0 && (i0 == e));
        const unsigned long long B = __ballot(m1 && (i1 == e));
        const int na = __popcll(A), nb = __popcll(B);
        if (lane == e) wcnt_mine = na + nb;
        if (m0 && (i0 == e)) offA = __popcll(A & lt);
        if (m1 && (i1 == e)) offB = na + __popcll(B & lt);
    }
    if (lane < E_NUM) wcnt[wv_id][lane] = wcnt_mine;
    __syncthreads();
    if (tid < E_NUM) {
        const int c0 = wcnt[0][tid], c1 = wcnt[1][tid], c2 = wcnt[2][tid], c3 = wcnt[3][tid];
        const int g = atomicAdd(&cnt[tid], c0 + c1 + c2 + c3);
        wbase[0][tid] = g;
        wbase[1][tid] = g + c0;
        wbase[2][tid] = g + c0 + c1;
        wbase[3][tid] = g + c0 + c1 + c2;
    }
    __syncthreads();

    if (m0) {
        const int pos = wbase[wv_id][i0] + offA;
        toklist[i0 * CAP + pos] = (token << 1);
        scalelist[i0 * CAP + pos] = rs * wn0;
    }
    if (m1) {
        const int pos = wbase[wv_id][i1] + offB;
        toklist[i1 * CAP + pos] = (token << 1) | 1;
        scalelist[i1 * CAP + pos] = rs * wn1;
    }
}

// ---------------- MFMA expert kernel ----------------
// LDS (bytes): w1T[128][104]f16 @0 (26624) | w2T[96][136]f16 @26624 (26112)
//              xb[32][104]f16 @52736 (6656) | Hs[32][136]f16 @59392 (8704)
//              b1s f32[128] @68096 | b2s f32[96] @68608 ; total 68992
// Strides 104/136 f16 (208/264B) keep ds_read_b128 at the 2-way (free) level.

template<bool GATHER>
__global__ __launch_bounds__(256, 2) void expert_kernel(
    const float* __restrict__ x,
    const float* __restrict__ W1, const float* __restrict__ b1,
    const float* __restrict__ W2, const float* __restrict__ b2,
    float* __restrict__ mixed, float* __restrict__ ybuf,
    const int* __restrict__ cnt, const int* __restrict__ toklist,
    const float* __restrict__ scalelist)
{
    __shared__ __align__(16) char smem[68992];
    _Float16* w1T = (_Float16*)(smem);            // [128 h][104 k(t)]
    _Float16* w2T = (_Float16*)(smem + 26624);    // [96 t][136 k(h)]
    _Float16* xb  = (_Float16*)(smem + 52736);    // [32 tok][104 t]
    _Float16* Hs  = (_Float16*)(smem + 59392);    // [32 tok][136 h]
    float*    b1s = (float*)(smem + 68096);
    float*    b2s = (float*)(smem + 68608);

    const int e = blockIdx.y;
    const int count = cnt[e];
    const int tid = threadIdx.x;

    const int* tl   = toklist   + (size_t)e * CAP;
    const float* sl = scalelist + (size_t)e * CAP;

    // ---- stage weights once per block ----
    const float4* gW1 = reinterpret_cast<const float4*>(W1 + (size_t)e * T_DIM * H_DIM);
    for (int q = tid; q < 3072; q += 256) {          // [96][128] -> w1T[h][t]
        const int t = q >> 5, hg = q & 31;           // coalesced float4 reads
        const float4 v = gW1[q];
        const int hb = hg * 4;
        w1T[(hb + 0) * 104 + t] = (_Float16)v.x;
        w1T[(hb + 1) * 104 + t] = (_Float16)v.y;
        w1T[(hb + 2) * 104 + t] = (_Float16)v.z;
        w1T[(hb + 3) * 104 + t] = (_Float16)v.w;
    }
    const float4* gW2 = reinterpret_cast<const float4*>(W2 + (size_t)e * H_DIM * T_DIM);
    for (int q = tid; q < 3072; q += 256) {          // [128][96] -> w2T[t][h]
        const int h = q / 24, qt = q % 24;
        const float4 v = gW2[q];
        const int tb = qt * 4;
        w2T[(tb + 0) * 136 + h] = (_Float16)v.x;
        w2T[(tb + 1) * 136 + h] = (_Float16)v.y;
        w2T[(tb + 2) * 136 + h] = (_Float16)v.z;
        w2T[(tb + 3) * 136 + h] = (_Float16)v.w;
    }
    if (tid < H_DIM) b1s[tid] = b1[e * H_DIM + tid];
    if (tid < T_DIM) b2s[tid] = b2[e * T_DIM + tid];

    const int w   = tid >> 6;         // wave 0..3
    const int lm  = tid & 15;         // lane & 15
    const int lg4 = (tid >> 4) & 3;   // lane >> 4
    const int m   = w & 1;            // M-tile (16 tokens)
    const int ng0 = (w >> 1) * 4;     // phase-1 N-tiles (4 of 8)
    const int tg0 = (w >> 1) * 3;     // phase-2 N-tiles (3 of 6)

    for (int t0 = blockIdx.x * 32; t0 < count; t0 += NBLK * 32) {
        const int nt = min(32, count - t0);

        // stage x -> xb (fp16)
#pragma unroll
        for (int i = 0; i < 3; ++i) {
            const int p = tid + i * 256;             // < 768
            const int tok = p / 24, tq = p % 24;
            const int slot = (tok < nt) ? tok : 0;
            const int row = tl[t0 + slot] >> 1;
            const float4 v = *reinterpret_cast<const float4*>(x + (size_t)row * T_DIM + tq * 4);
            f16x4 h4;
            h4[0] = (_Float16)v.x; h4[1] = (_Float16)v.y;
            h4[2] = (_Float16)v.z; h4[3] = (_Float16)v.w;
            *reinterpret_cast<f16x4*>(xb + tok * 104 + tq * 4) = h4;
        }
        __syncthreads();   // B1: xb (+ first-iter weights) staged

        // phase 1: H = relu(X@W1 + b1)
        f32x4 acc[4];
#pragma unroll
        for (int n = 0; n < 4; ++n) acc[n] = f32x4{0.f, 0.f, 0.f, 0.f};
#pragma unroll
        for (int ks = 0; ks < 3; ++ks) {
            const f16x8 a = *reinterpret_cast<const f16x8*>(xb + (m * 16 + lm) * 104 + ks * 32 + lg4 * 8);
#pragma unroll
            for (int n = 0; n < 4; ++n) {
                const f16x8 b = *reinterpret_cast<const f16x8*>(w1T + ((ng0 + n) * 16 + lm) * 104 + ks * 32 + lg4 * 8);
                acc[n] = __builtin_amdgcn_mfma_f32_16x16x32_f16(a, b, acc[n], 0, 0, 0);
            }
        }
#pragma unroll
        for (int n = 0; n < 4; ++n) {
            const int hid = (ng0 + n) * 16 + lm;
            const float bb = b1s[hid];
#pragma unroll
            for (int r = 0; r < 4; ++r) {
                const int tokl = m * 16 + lg4 * 4 + r;
                Hs[tokl * 136 + hid] = (_Float16)fmaxf(acc[n][r] + bb, 0.0f);
            }
        }
        __syncthreads();   // B2: Hs complete

        // phase 2: Y = H@W2
        f32x4 acc2[3];
#pragma unroll
        for (int n = 0; n < 3; ++n) acc2[n] = f32x4{0.f, 0.f, 0.f, 0.f};
#pragma unroll
        for (int ks = 0; ks < 4; ++ks) {
            const f16x8 a = *reinterpret_cast<const f16x8*>(Hs + (m * 16 + lm) * 136 + ks * 32 + lg4 * 8);
#pragma unroll
            for (int n = 0; n < 3; ++n) {
                const f16x8 b = *reinterpret_cast<const f16x8*>(w2T + ((tg0 + n) * 16 + lm) * 136 + ks * 32 + lg4 * 8);
                acc2[n] = __builtin_amdgcn_mfma_f32_16x16x32_f16(a, b, acc2[n], 0, 0, 0);
            }
        }

        // epilogue: ybuf[packed] = sc * (y + b2)
#pragma unroll
        for (int r = 0; r < 4; ++r) {
            const int tokl = m * 16 + lg4 * 4 + r;
            if (tokl < nt) {
                const int gi = t0 + tokl;
                const int packed = tl[gi];
                const float sc = sl[gi];
#pragma unroll
                for (int n = 0; n < 3; ++n) {
                    const int col = (tg0 + n) * 16 + lm;
                    const float v = sc * (acc2[n][r] + b2s[col]);
                    if (GATHER) ybuf[(size_t)packed * T_DIM + col] = v;
                    else atomicAdd(&mixed[(size_t)(packed >> 1) * T_DIM + col], v);
                }
            }
        }
        // no barrier needed here: next xb/Hs writes are fenced by B1/B2 above
    }
}

// mixed[tok] = coef*x[tok] + (mask&1 ? ybuf[2t] : 0) + (mask&2 ? ybuf[2t+1] : 0)
__global__ __launch_bounds__(256) void finalize_kernel(
    const float* __restrict__ x, const float* __restrict__ ybuf,
    const int* __restrict__ maskbuf, const float* __restrict__ coefbuf,
    float* __restrict__ mixed)
{
    const int tid = threadIdx.x;
    const int token = blockIdx.x * 32 + (tid >> 3);
    const int seg = (tid & 7) * 12;

    const float coef = coefbuf[token];
    const int mask = maskbuf[token];

    const float4* xs = reinterpret_cast<const float4*>(x + (size_t)token * T_DIM + seg);
    float4* od = reinterpret_cast<float4*>(mixed + (size_t)token * T_DIM + seg);

    float4 r[3];
#pragma unroll
    for (int q = 0; q < 3; ++q) {
        const float4 xv = xs[q];
        r[q] = make_float4(coef * xv.x, coef * xv.y, coef * xv.z, coef * xv.w);
    }
    if (mask & 1) {
        const float4* ys = reinterpret_cast<const float4*>(ybuf + (size_t)(2 * token) * T_DIM + seg);
#pragma unroll
        for (int q = 0; q < 3; ++q) {
            const float4 yv = ys[q];
            r[q].x += yv.x; r[q].y += yv.y; r[q].z += yv.z; r[q].w += yv.w;
        }
    }
    if (mask & 2) {
        const float4* ys = reinterpret_cast<const float4*>(ybuf + (size_t)(2 * token + 1) * T_DIM + seg);
#pragma unroll
        for (int q = 0; q < 3; ++q) {
            const float4 yv = ys[q];
            r[q].x += yv.x; r[q].y += yv.y; r[q].z += yv.z; r[q].w += yv.w;
        }
    }
#pragma unroll
    for (int q = 0; q < 3; ++q) od[q] = r[q];
}

extern "C" void kernel_launch(void* const* d_in, const int* in_sizes, int n_in,
                              void* d_out, int out_size, void* d_ws, size_t ws_size,
                              hipStream_t stream)
{
    const float* x  = (const float*)d_in[0];
    const float* Wg = (const float*)d_in[1];
    const float* bg = (const float*)d_in[2];
    const float* W1 = (const float*)d_in[3];
    const float* b1 = (const float*)d_in[4];
    const float* W2 = (const float*)d_in[5];
    const float* b2 = (const float*)d_in[6];
    const float* rs = (const float*)d_in[7];

    float* mixed = (float*)d_out;
    float* util  = mixed + (size_t)BN_TOTAL * T_DIM;

    char* ws = (char*)d_ws;
    int*   cnt       = (int*)ws;
    int*   toklist   = (int*)(ws + OFF_TOK);
    float* scalelist = (float*)(ws + OFF_SCALE);
    int*   maskbuf   = (int*)(ws + OFF_MASK);
    float* coefbuf   = (float*)(ws + OFF_COEF);
    float* ybuf      = (float*)(ws + OFF_YBUF);

    const bool gather = (ws_size >= WS_NEED);

    hipMemsetAsync(cnt, 0, 32, stream);
    if (gather) {
        gate_kernel<true><<<BN_TOTAL / 256, 256, 0, stream>>>(
            x, Wg, bg, rs, mixed, util, cnt, toklist, scalelist, maskbuf, coefbuf);
        expert_kernel<true><<<dim3(NBLK, E_NUM), 256, 0, stream>>>(
            x, W1, b1, W2, b2, mixed, ybuf, cnt, toklist, scalelist);
        finalize_kernel<<<BN_TOTAL / 32, 256, 0, stream>>>(
            x, ybuf, maskbuf, coefbuf, mixed);
    } else {
        gate_kernel<false><<<BN_TOTAL / 256, 256, 0, stream>>>(
            x, Wg, bg, rs, mixed, util, cnt, toklist, scalelist, maskbuf, coefbuf);
        expert_kernel<false><<<dim3(NBLK, E_NUM), 256, 0, stream>>>(
            x, W1, b1, W2, b2, mixed, ybuf, cnt, toklist, scalelist);
    }
}

// Round 6
// 98.883 us; speedup vs baseline: 18.8364x; 1.2708x over previous
//
#include <hip/hip_runtime.h>
#include <hip/hip_bf16.h>

#define BN_TOTAL   131072      // B*N
#define T_DIM      96
#define E_NUM      8
#define H_DIM      128
#define CAP        131072
#define PTHRESH    0.05f
#define NBLK       64          // expert-kernel blocks per expert

typedef _Float16 f16x8 __attribute__((ext_vector_type(8)));
typedef _Float16 f16x4 __attribute__((ext_vector_type(4)));
typedef float    f32x4 __attribute__((ext_vector_type(4)));

// ---- workspace layout (bytes) ----
#define OFF_TOK    1024
#define OFF_SCALE  (OFF_TOK   + E_NUM * CAP * 4)
#define OFF_MASK   (OFF_SCALE + E_NUM * CAP * 4)
#define OFF_COEF   (OFF_MASK  + BN_TOTAL * 4)
#define OFF_YBUF   (OFF_COEF  + BN_TOTAL * 4)
#define WS_NEED    ((size_t)OFF_YBUF + (size_t)2 * BN_TOTAL * T_DIM * 4)

// toklist entries PACKED: (token<<1)|k ; ybuf row id == packed value (< 2*BN).
// ybuf stored as _Float16 (fits in half the reserved region).

template<bool GATHER>
__global__ __launch_bounds__(256) void gate_kernel(
    const float* __restrict__ x, const float* __restrict__ Wg,
    const float* __restrict__ bg, const float* __restrict__ rs_p,
    float* __restrict__ mixed, float* __restrict__ util,
    int* __restrict__ cnt, int* __restrict__ toklist, float* __restrict__ scalelist,
    int* __restrict__ maskbuf, float* __restrict__ coefbuf)
{
    __shared__ float wg_s[E_NUM][T_DIM];
    __shared__ float bg_s[E_NUM];
    __shared__ int wcnt[4][E_NUM];
    __shared__ int wbase[4][E_NUM];

    const int tid = threadIdx.x;
    for (int i = tid; i < E_NUM * T_DIM; i += 256) wg_s[i / T_DIM][i % T_DIM] = Wg[i];
    if (tid < E_NUM) bg_s[tid] = bg[tid];
    __syncthreads();

    const int token = blockIdx.x * 256 + tid;
    const float4* x4 = reinterpret_cast<const float4*>(x + (size_t)token * T_DIM);

    float logit[E_NUM];
#pragma unroll
    for (int e = 0; e < E_NUM; ++e) logit[e] = 0.0f;

#pragma unroll 4
    for (int i = 0; i < T_DIM / 4; ++i) {
        const float4 xv = x4[i];
#pragma unroll
        for (int e = 0; e < E_NUM; ++e) {
            const float4 wv = *reinterpret_cast<const float4*>(&wg_s[e][4 * i]);
            logit[e] = fmaf(xv.x, wv.x, logit[e]);
            logit[e] = fmaf(xv.y, wv.y, logit[e]);
            logit[e] = fmaf(xv.z, wv.z, logit[e]);
            logit[e] = fmaf(xv.w, wv.w, logit[e]);
        }
    }
#pragma unroll
    for (int e = 0; e < E_NUM; ++e) logit[e] = (logit[e] + bg_s[e]) / 10.0f;

    float mx = logit[0];
#pragma unroll
    for (int e = 1; e < E_NUM; ++e) mx = fmaxf(mx, logit[e]);
    float p[E_NUM]; float s = 0.0f;
#pragma unroll
    for (int e = 0; e < E_NUM; ++e) { p[e] = __expf(logit[e] - mx); s += p[e]; }
    const float inv_s = 1.0f / s;
#pragma unroll
    for (int e = 0; e < E_NUM; ++e) p[e] *= inv_s;

    int i0 = 0; float p0 = p[0];
#pragma unroll
    for (int e = 1; e < E_NUM; ++e) { if (p[e] > p0) { p0 = p[e]; i0 = e; } }
    int i1 = -1; float p1 = -1.0f;
#pragma unroll
    for (int e = 0; e < E_NUM; ++e) { if (e != i0 && p[e] > p1) { p1 = p[e]; i1 = e; } }

    const float denom0 = p0 + p1 + 1e-12f;
    const float w0 = p0 / denom0, w1 = p1 / denom0;
    const bool m0 = (w0 >= PTHRESH), m1 = (w1 >= PTHRESH);
    const float sumw = w0 + w1;
    const float denom1 = fmaxf(sumw, 1e-12f);
    const float wn0 = w0 / denom1, wn1 = w1 / denom1;
    const float rs = *rs_p;

    float u[E_NUM];
#pragma unroll
    for (int e = 0; e < E_NUM; ++e)
        u[e] = (((e == i0) && m0) || ((e == i1) && m1)) ? 1.0f : 0.0f;
    float4* u4 = reinterpret_cast<float4*>(util + (size_t)token * E_NUM);
    u4[0] = make_float4(u[0], u[1], u[2], u[3]);
    u4[1] = make_float4(u[4], u[5], u[6], u[7]);

    const float coef = rs * (wn0 + wn1);
    if (GATHER) {
        coefbuf[token] = coef;
        maskbuf[token] = (m0 ? 1 : 0) | (m1 ? 2 : 0);
    } else {
        float4* o4 = reinterpret_cast<float4*>(mixed + (size_t)token * T_DIM);
#pragma unroll 4
        for (int i = 0; i < T_DIM / 4; ++i) {
            const float4 xv = x4[i];
            o4[i] = make_float4(coef * xv.x, coef * xv.y, coef * xv.z, coef * xv.w);
        }
    }

    // ---- two-level aggregated routing-list append ----
    const int lane = tid & 63;
    const int wv_id = tid >> 6;
    const unsigned long long lt = (1ULL << lane) - 1ULL;

    int wcnt_mine = 0, offA = 0, offB = 0;
#pragma unroll
    for (int e = 0; e < E_NUM; ++e) {
        const unsigned long long A = __ballot(m0 && (i0 == e));
        const unsigned long long B = __ballot(m1 && (i1 == e));
        const int na = __popcll(A), nb = __popcll(B);
        if (lane == e) wcnt_mine = na + nb;
        if (m0 && (i0 == e)) offA = __popcll(A & lt);
        if (m1 && (i1 == e)) offB = na + __popcll(B & lt);
    }
    if (lane < E_NUM) wcnt[wv_id][lane] = wcnt_mine;
    __syncthreads();
    if (tid < E_NUM) {
        const int c0 = wcnt[0][tid], c1 = wcnt[1][tid], c2 = wcnt[2][tid], c3 = wcnt[3][tid];
        const int g = atomicAdd(&cnt[tid], c0 + c1 + c2 + c3);
        wbase[0][tid] = g;
        wbase[1][tid] = g + c0;
        wbase[2][tid] = g + c0 + c1;
        wbase[3][tid] = g + c0 + c1 + c2;
    }
    __syncthreads();

    if (m0) {
        const int pos = wbase[wv_id][i0] + offA;
        toklist[i0 * CAP + pos] = (token << 1);
        scalelist[i0 * CAP + pos] = rs * wn0;
    }
    if (m1) {
        const int pos = wbase[wv_id][i1] + offB;
        toklist[i1 * CAP + pos] = (token << 1) | 1;
        scalelist[i1 * CAP + pos] = rs * wn1;
    }
}

// ---------------- MFMA expert kernel: weights in REGISTERS ----------------
// LDS: xb[64][104] f16 (13312 B) + Hs[64][136] f16 (17408 B) = 30720 B.
// Per thread: 12 W1-frags + 12 W2-frags (f16x8, 96 VGPRs), loaded once from
// global (L2-resident) in MFMA lane layout. No LDS weight staging at all.

template<bool GATHER>
__global__ __launch_bounds__(256, 2) void expert_kernel(
    const float* __restrict__ x,
    const float* __restrict__ W1, const float* __restrict__ b1,
    const float* __restrict__ W2, const float* __restrict__ b2,
    float* __restrict__ mixed, _Float16* __restrict__ ybh,
    const int* __restrict__ cnt, const int* __restrict__ toklist,
    const float* __restrict__ scalelist)
{
    __shared__ __align__(16) _Float16 xb[64 * 104];
    __shared__ __align__(16) _Float16 Hs[64 * 136];

    const int e = blockIdx.y;
    const int count = cnt[e];
    const int tid = threadIdx.x;
    const int lane = tid & 63;
    const int w = tid >> 6;          // wave 0..3
    const int lm = lane & 15;
    const int lg4 = lane >> 4;       // 0..3
    const int mhalf = w & 1;         // m-tiles {mhalf*2, mhalf*2+1}
    const int nhalf = w >> 1;        // n-half

    const int* tl   = toklist   + (size_t)e * CAP;
    const float* sl = scalelist + (size_t)e * CAP;

    // ---- load W fragments into registers (once per block) ----
    const float* gW1 = W1 + (size_t)e * T_DIM * H_DIM;   // [96 t][128 h]
    f16x8 w1f[3][4];
#pragma unroll
    for (int ks = 0; ks < 3; ++ks)
#pragma unroll
        for (int n = 0; n < 4; ++n) {
            const int h = nhalf * 64 + n * 16 + lm;
#pragma unroll
            for (int j = 0; j < 8; ++j) {
                const int t = ks * 32 + lg4 * 8 + j;
                w1f[ks][n][j] = (_Float16)gW1[t * H_DIM + h];
            }
        }
    const float* gW2 = W2 + (size_t)e * H_DIM * T_DIM;   // [128 h][96 t]
    f16x8 w2f[4][3];
#pragma unroll
    for (int ks = 0; ks < 4; ++ks)
#pragma unroll
        for (int n = 0; n < 3; ++n) {
            const int t = nhalf * 48 + n * 16 + lm;
#pragma unroll
            for (int j = 0; j < 8; ++j) {
                const int kh = ks * 32 + lg4 * 8 + j;
                w2f[ks][n][j] = (_Float16)gW2[kh * T_DIM + t];
            }
        }
    float b1r[4], b2r[3];
#pragma unroll
    for (int n = 0; n < 4; ++n) b1r[n] = b1[e * H_DIM + nhalf * 64 + n * 16 + lm];
#pragma unroll
    for (int n = 0; n < 3; ++n) b2r[n] = b2[e * T_DIM + nhalf * 48 + n * 16 + lm];

    for (int t0 = blockIdx.x * 64; t0 < count; t0 += NBLK * 64) {
        const int nt = min(64, count - t0);

        // stage x -> xb fp16 ([64 tok][104 t])
#pragma unroll
        for (int i = 0; i < 6; ++i) {
            const int p = tid + i * 256;            // < 1536
            const int tok = p / 24, tq = p % 24;
            const int slot = (tok < nt) ? tok : 0;
            const int row = tl[t0 + slot] >> 1;
            const float4 v = *reinterpret_cast<const float4*>(x + (size_t)row * T_DIM + tq * 4);
            f16x4 h4;
            h4[0] = (_Float16)v.x; h4[1] = (_Float16)v.y;
            h4[2] = (_Float16)v.z; h4[3] = (_Float16)v.w;
            *reinterpret_cast<f16x4*>(xb + tok * 104 + tq * 4) = h4;
        }
        __syncthreads();   // B1: xb staged

        // phase 1: H = relu(X@W1 + b1)
        f32x4 acc1[2][4];
#pragma unroll
        for (int mi = 0; mi < 2; ++mi)
#pragma unroll
            for (int n = 0; n < 4; ++n) acc1[mi][n] = f32x4{0.f, 0.f, 0.f, 0.f};
#pragma unroll
        for (int ks = 0; ks < 3; ++ks) {
            const f16x8 a0 = *reinterpret_cast<const f16x8*>(xb + ((mhalf * 2 + 0) * 16 + lm) * 104 + ks * 32 + lg4 * 8);
            const f16x8 a1 = *reinterpret_cast<const f16x8*>(xb + ((mhalf * 2 + 1) * 16 + lm) * 104 + ks * 32 + lg4 * 8);
#pragma unroll
            for (int n = 0; n < 4; ++n) {
                acc1[0][n] = __builtin_amdgcn_mfma_f32_16x16x32_f16(a0, w1f[ks][n], acc1[0][n], 0, 0, 0);
                acc1[1][n] = __builtin_amdgcn_mfma_f32_16x16x32_f16(a1, w1f[ks][n], acc1[1][n], 0, 0, 0);
            }
        }
        // relu + bias -> Hs ([64 tok][136 h])
#pragma unroll
        for (int mi = 0; mi < 2; ++mi)
#pragma unroll
            for (int n = 0; n < 4; ++n) {
                const int hid = nhalf * 64 + n * 16 + lm;
#pragma unroll
                for (int r = 0; r < 4; ++r) {
                    const int tok = (mhalf * 2 + mi) * 16 + lg4 * 4 + r;
                    Hs[tok * 136 + hid] = (_Float16)fmaxf(acc1[mi][n][r] + b1r[n], 0.0f);
                }
            }
        __syncthreads();   // B2: Hs complete (also fences xb reads)

        // phase 2: Y = H@W2
        f32x4 acc2[2][3];
#pragma unroll
        for (int mi = 0; mi < 2; ++mi)
#pragma unroll
            for (int n = 0; n < 3; ++n) acc2[mi][n] = f32x4{0.f, 0.f, 0.f, 0.f};
#pragma unroll
        for (int ks = 0; ks < 4; ++ks) {
            const f16x8 a0 = *reinterpret_cast<const f16x8*>(Hs + ((mhalf * 2 + 0) * 16 + lm) * 136 + ks * 32 + lg4 * 8);
            const f16x8 a1 = *reinterpret_cast<const f16x8*>(Hs + ((mhalf * 2 + 1) * 16 + lm) * 136 + ks * 32 + lg4 * 8);
#pragma unroll
            for (int n = 0; n < 3; ++n) {
                acc2[0][n] = __builtin_amdgcn_mfma_f32_16x16x32_f16(a0, w2f[ks][n], acc2[0][n], 0, 0, 0);
                acc2[1][n] = __builtin_amdgcn_mfma_f32_16x16x32_f16(a1, w2f[ks][n], acc2[1][n], 0, 0, 0);
            }
        }

        // epilogue: ybh[packed] = f16( sc * (y + b2) )
#pragma unroll
        for (int mi = 0; mi < 2; ++mi)
#pragma unroll
            for (int r = 0; r < 4; ++r) {
                const int tokl = (mhalf * 2 + mi) * 16 + lg4 * 4 + r;
                if (tokl < nt) {
                    const int gi = t0 + tokl;
                    const int packed = tl[gi];
                    const float sc = sl[gi];
#pragma unroll
                    for (int n = 0; n < 3; ++n) {
                        const int col = nhalf * 48 + n * 16 + lm;
                        const float v = sc * (acc2[mi][n][r] + b2r[n]);
                        if (GATHER) ybh[(size_t)packed * T_DIM + col] = (_Float16)v;
                        else atomicAdd(&mixed[(size_t)(packed >> 1) * T_DIM + col], v);
                    }
                }
            }
    }
}

// mixed[tok] = coef*x[tok] + (mask&1 ? ybh[2t] : 0) + (mask&2 ? ybh[2t+1] : 0)
__global__ __launch_bounds__(256) void finalize_kernel(
    const float* __restrict__ x, const _Float16* __restrict__ ybh,
    const int* __restrict__ maskbuf, const float* __restrict__ coefbuf,
    float* __restrict__ mixed)
{
    const int tid = threadIdx.x;
    const int token = blockIdx.x * 32 + (tid >> 3);
    const int seg = (tid & 7) * 12;

    const float coef = coefbuf[token];
    const int mask = maskbuf[token];

    const float4* xs = reinterpret_cast<const float4*>(x + (size_t)token * T_DIM + seg);
    float4* od = reinterpret_cast<float4*>(mixed + (size_t)token * T_DIM + seg);

    float4 r[3];
#pragma unroll
    for (int q = 0; q < 3; ++q) {
        const float4 xv = xs[q];
        r[q] = make_float4(coef * xv.x, coef * xv.y, coef * xv.z, coef * xv.w);
    }
    if (mask & 1) {
        const f16x4* ys = reinterpret_cast<const f16x4*>(ybh + (size_t)(2 * token) * T_DIM + seg);
#pragma unroll
        for (int q = 0; q < 3; ++q) {
            const f16x4 yv = ys[q];
            r[q].x += (float)yv[0]; r[q].y += (float)yv[1];
            r[q].z += (float)yv[2]; r[q].w += (float)yv[3];
        }
    }
    if (mask & 2) {
        const f16x4* ys = reinterpret_cast<const f16x4*>(ybh + (size_t)(2 * token + 1) * T_DIM + seg);
#pragma unroll
        for (int q = 0; q < 3; ++q) {
            const f16x4 yv = ys[q];
            r[q].x += (float)yv[0]; r[q].y += (float)yv[1];
            r[q].z += (float)yv[2]; r[q].w += (float)yv[3];
        }
    }
#pragma unroll
    for (int q = 0; q < 3; ++q) od[q] = r[q];
}

extern "C" void kernel_launch(void* const* d_in, const int* in_sizes, int n_in,
                              void* d_out, int out_size, void* d_ws, size_t ws_size,
                              hipStream_t stream)
{
    const float* x  = (const float*)d_in[0];
    const float* Wg = (const float*)d_in[1];
    const float* bg = (const float*)d_in[2];
    const float* W1 = (const float*)d_in[3];
    const float* b1 = (const float*)d_in[4];
    const float* W2 = (const float*)d_in[5];
    const float* b2 = (const float*)d_in[6];
    const float* rs = (const float*)d_in[7];

    float* mixed = (float*)d_out;
    float* util  = mixed + (size_t)BN_TOTAL * T_DIM;

    char* ws = (char*)d_ws;
    int*      cnt       = (int*)ws;
    int*      toklist   = (int*)(ws + OFF_TOK);
    float*    scalelist = (float*)(ws + OFF_SCALE);
    int*      maskbuf   = (int*)(ws + OFF_MASK);
    float*    coefbuf   = (float*)(ws + OFF_COEF);
    _Float16* ybh       = (_Float16*)(ws + OFF_YBUF);

    const bool gather = (ws_size >= WS_NEED);

    hipMemsetAsync(cnt, 0, 32, stream);
    if (gather) {
        gate_kernel<true><<<BN_TOTAL / 256, 256, 0, stream>>>(
            x, Wg, bg, rs, mixed, util, cnt, toklist, scalelist, maskbuf, coefbuf);
        expert_kernel<true><<<dim3(NBLK, E_NUM), 256, 0, stream>>>(
            x, W1, b1, W2, b2, mixed, ybh, cnt, toklist, scalelist);
        finalize_kernel<<<BN_TOTAL / 32, 256, 0, stream>>>(
            x, ybh, maskbuf, coefbuf, mixed);
    } else {
        gate_kernel<false><<<BN_TOTAL / 256, 256, 0, stream>>>(
            x, Wg, bg, rs, mixed, util, cnt, toklist, scalelist, maskbuf, coefbuf);
        expert_kernel<false><<<dim3(NBLK, E_NUM), 256, 0, stream>>>(
            x, W1, b1, W2, b2, mixed, ybh, cnt, toklist, scalelist);
    }
}